// Round 8
// baseline (242.172 us; speedup 1.0000x reference)
//
#include <hip/hip_runtime.h>

// CIN cross-network, fused MFMA implementation (f16 inputs, fp32 accum).
// Round 11: 8 PRIVATE BATCHES PER WAVE (2-wave, 128-thr blocks).
//  - New bottleneck analysis: each wave streams the full 640KB W from L2
//    per 4 batches -> 2.62GB total = 19TB/s = 55% of L2 ceiling, co-limiting
//    with MFMA (58%). At perfect MFMA util the 4-batch structure would need
//    92% of L2 ceiling -> W traffic, not scheduling, is the wall.
//  - 8 batches/wave halves W traffic (Bf load amortized over 32 MFMAs).
//    Same 16 batches and 53248B LDS per block -> still 3 blocks/CU.
//  - W repack reverted to round-5 t-major (kb-major measured worse, r10).
//  - launch_bounds(128,2): VGPR budget 256 for acc(128)+av(64)+Bf+misc.
//    No unroll pragma on m-loop: let compiler schedule under pressure.
// Carried over verified pieces: 16x16x32 fragments, m-major x0, d-major xk
// (pad 72), no barriers (all LDS wave-private), verified epilogue mapping.

typedef _Float16 half8 __attribute__((ext_vector_type(8)));
typedef _Float16 half4 __attribute__((ext_vector_type(4)));
typedef _Float16 half2v __attribute__((ext_vector_type(2)));
typedef float f32x4 __attribute__((ext_vector_type(4)));

#define OUT_STRIDE 192
#define X0B 512   // x0 batch stride (m-major: m*16 + d, 32x16 halfs)
#define XKR 72    // xk row stride: 64 + 8 pad (16B-aligned)
#define XKB 1152  // xk batch stride

// ---------------------------------------------------------------------------
// Fused weight repack (round-5 verified t-major layout, all 3 layers):
// dst[base + ((t*NKB + kb)*64 + lane)*8 + j] =
//     (f16) W[k -> (m,h)][n = t*16 + (lane&15)],  k = kb*32 + (lane>>4)*8 + j
__global__ void prep_w_all(const float* __restrict__ W0,
                           const float* __restrict__ W1,
                           const float* __restrict__ W2,
                           _Float16* __restrict__ dst) {
  int e = blockIdx.x * 256 + threadIdx.x;   // e < 327680
  const float* W;
  int logH, nkbLog, le;
  if (e < 65536)       { W = W0; logH = 5; nkbLog = 5; le = e; }
  else if (e < 196608) { W = W1; logH = 6; nkbLog = 6; le = e - 65536; }
  else                 { W = W2; logH = 6; nkbLog = 6; le = e - 196608; }
  int j    = le & 7;
  int lane = (le >> 3) & 63;
  int rr   = lane & 15, qq = lane >> 4;
  int rest = le >> 9;
  int kb   = rest & ((1 << nkbLog) - 1);
  int t    = rest >> nkbLog;
  int k    = kb * 32 + qq * 8 + j;
  int H    = 1 << logH;
  int m    = k >> logH, h = k & (H - 1);
  int n    = t * 16 + rr;
  dst[e] = (_Float16)W[(m * H + h) * 64 + n];
}

// ---------------------------------------------------------------------------
// One layer for one wave's 8 private batches.
// NHI: number of 32-wide h-blocks (1 for H=32, 2 for H=64). K-blocks: NKB=32*NHI.
// av[b][hi] = xk-vector (8 f16 at h = hi*32 + q*8 + j) held in registers.
// x0s is M-MAJOR: x0s[b*X0B + m*16 + d].
template<int NHI, bool LAST>
__device__ __forceinline__ void run_layer(
    const _Float16* __restrict__ Wp, const half8 (&av)[8][NHI],
    const _Float16* x0s, _Float16* xkw, float* __restrict__ out,
    long gb0, int loff, int lane, int r, int q)
{
  const int NKB = 32 * NHI;
  f32x4 acc[8][4];
#pragma unroll
  for (int b = 0; b < 8; ++b)
#pragma unroll
    for (int t = 0; t < 4; ++t) acc[b][t] = (f32x4){0.f, 0.f, 0.f, 0.f};

  const _Float16* Wl = Wp + lane * 8;

  for (int m = 0; m < 32; ++m) {
    // x0 scalar per batch for this m (m-major: conflict-free, r5-verified).
    half2v xs2[8];
#pragma unroll
    for (int b = 0; b < 8; ++b) {
      _Float16 x = x0s[b * X0B + m * 16 + r];
      xs2[b] = (half2v){x, x};
    }
#pragma unroll
    for (int hi = 0; hi < NHI; ++hi) {
      const int kb = m * NHI + hi;
      half8 Bf[4];
#pragma unroll
      for (int t = 0; t < 4; ++t)
        Bf[t] = *(const half8*)(Wl + (size_t)(t * NKB + kb) * 512);
      // 8 batches share the 4 Bf fragments: 32 MFMAs per 4KB of W.
#pragma unroll
      for (int b = 0; b < 8; ++b) {
        half8 af;
        half2v* ap = (half2v*)&af;
        const half2v* vp = (const half2v*)&av[b][hi];
#pragma unroll
        for (int j2 = 0; j2 < 4; ++j2) ap[j2] = vp[j2] * xs2[b];
#pragma unroll
        for (int t = 0; t < 4; ++t)
          acc[b][t] = __builtin_amdgcn_mfma_f32_16x16x32_f16(
              af, Bf[t], acc[b][t], 0, 0, 0);
      }
    }
  }

  // Epilogue (round-5 verified). C/D layout: col n = r, row d = q*4 + reg.
#pragma unroll
  for (int b = 0; b < 8; ++b) {
#pragma unroll
    for (int t = 0; t < 4; ++t) {
      float s = 0.f;
#pragma unroll
      for (int rr = 0; rr < 4; ++rr) {
        float v = acc[b][t][rr];
        v = v > 0.f ? v : 0.f;
        s += v;
        if (!LAST)
          xkw[b * XKB + (q * 4 + rr) * XKR + t * 16 + r] = (_Float16)v;
      }
      s += __shfl_xor(s, 16);
      s += __shfl_xor(s, 32);
      if (q == 0)
        out[(gb0 + b) * OUT_STRIDE + loff + t * 16 + r] = s;
    }
  }
}

__global__ __launch_bounds__(128, 2) void cin_main(
    const float* __restrict__ emb, const _Float16* __restrict__ Wall,
    float* __restrict__ out)
{
  // Per block (2 waves x 8 batches = 16 batches):
  // x0: 16 * 512 f16 (m-major) = 16384 B
  // xk: 16 * 1152 f16 (d-major, pad 72) = 36864 B
  // total 53248 B -> 3 blocks/CU = 6 waves/CU.
  __shared__ __align__(16) _Float16 lds[16 * X0B + 16 * XKB];
  const int lane = threadIdx.x & 63;
  const int wv = threadIdx.x >> 6;         // 0..1
  const int r = lane & 15, q = lane >> 4;
  const long gb0 = (long)blockIdx.x * 16 + wv * 8;

  _Float16* x0w = &lds[wv * 8 * X0B];
  _Float16* xkw = &lds[16 * X0B + wv * 8 * XKB];

  // Stage this wave's 8 batches: emb is (m,d) row-major = the LDS layout.
#pragma unroll
  for (int bb = 0; bb < 8; ++bb) {
    const float* src = emb + (gb0 + bb) * 512;
    _Float16* dstb = x0w + bb * X0B;
#pragma unroll
    for (int i = 0; i < 2; ++i) {
      int f = i * 256 + lane * 4;
      float4 v = *(const float4*)(src + f);
      half4 h = {(_Float16)v.x, (_Float16)v.y, (_Float16)v.z, (_Float16)v.w};
      *(half4*)(dstb + f) = h;
    }
  }
  // All LDS regions are wave-private: program order + waitcnt suffice.

  // Layer 1: A-vectors from x0 (xk==x0, indexed by h along the m axis).
  // m-major layout -> 8 strided u16 reads per batch (one-time, outside loop).
  half8 av1[8][1];
#pragma unroll
  for (int b = 0; b < 8; ++b) {
#pragma unroll
    for (int j = 0; j < 8; ++j)
      av1[b][0][j] = x0w[b * X0B + (q * 8 + j) * 16 + r];
  }
  run_layer<1, false>(Wall, av1, x0w, xkw, out, gb0, 0, lane, r, q);

  // Layer 2: A-vectors from xk (h = hi*32 + q*8 + j), d-major xk layout.
  half8 av2[8][2];
#pragma unroll
  for (int b = 0; b < 8; ++b)
#pragma unroll
    for (int hi = 0; hi < 2; ++hi)
      av2[b][hi] = *(const half8*)(xkw + b * XKB + r * XKR + hi * 32 + q * 8);
  run_layer<2, false>(Wall + 65536, av2, x0w, xkw, out, gb0, 64, lane, r, q);

  // Layer 3: reload A-vectors (layer 2 rewrote xk).
#pragma unroll
  for (int b = 0; b < 8; ++b)
#pragma unroll
    for (int hi = 0; hi < 2; ++hi)
      av2[b][hi] = *(const half8*)(xkw + b * XKB + r * XKR + hi * 32 + q * 8);
  run_layer<2, true>(Wall + 196608, av2, x0w, xkw, out, gb0, 128, lane, r, q);
}

extern "C" void kernel_launch(void* const* d_in, const int* in_sizes, int n_in,
                              void* d_out, int out_size, void* d_ws, size_t ws_size,
                              hipStream_t stream) {
  const float* emb = (const float*)d_in[0];
  const float* W0  = (const float*)d_in[1];
  const float* W1  = (const float*)d_in[2];
  const float* W2  = (const float*)d_in[3];
  float* out = (float*)d_out;
  _Float16* ws = (_Float16*)d_ws;   // needs 327680 f16 = 640 KB

  // Single fused weight repack (327680 elements).
  prep_w_all<<<1280, 256, 0, stream>>>(W0, W1, W2, ws);

  // 16384 batches / 16 per block = 1024 blocks of 128 threads (2 waves x 8 b).
  cin_main<<<1024, 128, 0, stream>>>(emb, ws, out);
}

// Round 9
// 207.736 us; speedup vs baseline: 1.1658x; 1.1658x over previous
//
#include <hip/hip_runtime.h>

// CIN cross-network, fused MFMA implementation (f16 inputs, fp32 accum).
// Round 12: round-5 structure (best verified, 138.4us) with two
// instruction-deletion changes, one per kernel:
//  (1) cin_main: x0 stored D-MAJOR pad-34 (x0[d][m], stride 34 halfs ->
//      17*r dword index, conflict-free). Per-m scalars read PAIRED: one
//      ds_read_b32 serves m and m+1; lo/hi broadcast folds into
//      v_pk_mul_f16 op_sel (no added VALU). 384 -> 192 LDS scalar reads
//      per wave, each with 2-m latency slack. Explicit mp-loop with
//      #pragma unroll 1 keeps the verified 2-m body (round-4 lesson).
//  (2) prep_w: inverted mapping, thread <-> 4 consecutive source floats
//      (coalesced float4 reads, was stride-256B/lane), 4 u16 scatter
//      writes. Same round-5-verified bijection.
// Occupancy-preserving: LDS 54272B -> still 3 blocks/CU (12 waves/CU).
// All LDS wave-private => no barriers. Falsified-and-reverted: 32x32 MFMA
// (r6-8), source prefetch (r9), kb-major W (r10), 8 batches/wave (r11).

typedef _Float16 half8 __attribute__((ext_vector_type(8)));
typedef _Float16 half4 __attribute__((ext_vector_type(4)));
typedef _Float16 half2v __attribute__((ext_vector_type(2)));
typedef float f32x4 __attribute__((ext_vector_type(4)));

#define OUT_STRIDE 192
#define X0R 34    // x0 row stride (d-major: d*34 + m), pad 2 -> conflict-free
#define X0B 544   // x0 batch stride (16 rows * 34)
#define XKR 72    // xk row stride: 64 + 8 pad (16B-aligned)
#define XKB 1152  // xk batch stride

// ---------------------------------------------------------------------------
// Fused weight repack (round-5 verified t-major layout), source-coalesced:
// thread <-> 4 consecutive W floats; dst e = ((t*NKB+kb)*64 + lane)*8 + j
// with k = kb*32 + (lane>>4)*8 + j (= m*H + h), n = t*16 + (lane&15).
__global__ void prep_w_all(const float* __restrict__ W0,
                           const float* __restrict__ W1,
                           const float* __restrict__ W2,
                           _Float16* __restrict__ dst) {
  int g = blockIdx.x * 256 + threadIdx.x;   // g < 81920 float4-groups
  const float* W;
  int nkb, dbase, lg;
  if (g < 16384)      { W = W0; nkb = 32; dbase = 0;      lg = g; }
  else if (g < 49152) { W = W1; nkb = 64; dbase = 65536;  lg = g - 16384; }
  else                { W = W2; nkb = 64; dbase = 196608; lg = g - 49152; }
  int s  = lg * 4;                  // flat source index: s = k*64 + n
  int k  = s >> 6;
  int n0 = s & 63;                  // multiple of 4
  float4 v = *(const float4*)(W + s);
  int kb = k >> 5, qq = (k >> 3) & 3, j = k & 7;
  float vv[4] = {v.x, v.y, v.z, v.w};
#pragma unroll
  for (int i = 0; i < 4; ++i) {
    int n = n0 + i;
    int t = n >> 4, rr = n & 15;
    int lane = qq * 16 + rr;
    dst[dbase + (((t * nkb + kb) * 64 + lane) << 3) + j] = (_Float16)vv[i];
  }
}

// ---------------------------------------------------------------------------
// One (m, *) group: af = av * xs2 broadcast, 16 MFMAs.
template<int NHI>
__device__ __forceinline__ void do_group(
    const _Float16* __restrict__ Wl, const half8 (&av)[4][NHI],
    const half2v (&xs2)[4], f32x4 (&acc)[4][4], int m)
{
  const int NKB = 32 * NHI;
#pragma unroll
  for (int hi = 0; hi < NHI; ++hi) {
    const int kb = m * NHI + hi;
    half8 Bf[4];
#pragma unroll
    for (int t = 0; t < 4; ++t)
      Bf[t] = *(const half8*)(Wl + (size_t)(t * NKB + kb) * 512);
#pragma unroll
    for (int b = 0; b < 4; ++b) {
      half8 af;
      half2v* ap = (half2v*)&af;
      const half2v* vp = (const half2v*)&av[b][hi];
#pragma unroll
      for (int j2 = 0; j2 < 4; ++j2) ap[j2] = vp[j2] * xs2[b];
#pragma unroll
      for (int t = 0; t < 4; ++t)
        acc[b][t] = __builtin_amdgcn_mfma_f32_16x16x32_f16(
            af, Bf[t], acc[b][t], 0, 0, 0);
    }
  }
}

// ---------------------------------------------------------------------------
// One layer for one wave's 4 private batches.
// NHI: number of 32-wide h-blocks (1 for H=32, 2 for H=64).
// av[b][hi] = xk-vector (8 f16 at h = hi*32 + q*8 + j) held in registers.
// x0s is D-MAJOR pad-34: x0s[b*X0B + d*X0R + m].
template<int NHI, bool LAST>
__device__ __forceinline__ void run_layer(
    const _Float16* __restrict__ Wp, const half8 (&av)[4][NHI],
    const _Float16* x0s, _Float16* xkw, float* __restrict__ out,
    long gb0, int loff, int lane, int r, int q)
{
  f32x4 acc[4][4];
#pragma unroll
  for (int b = 0; b < 4; ++b)
#pragma unroll
    for (int t = 0; t < 4; ++t) acc[b][t] = (f32x4){0.f, 0.f, 0.f, 0.f};

  const _Float16* Wl = Wp + lane * 8;
  const _Float16* x0l = x0s + r * X0R;   // this lane's d-row

  // 16 m-pairs; one ds_read_b32 per batch serves both m's (lo/hi via
  // op_sel in v_pk_mul). unroll 1: keep the verified 2-m body size.
#pragma unroll 1
  for (int mp = 0; mp < 16; ++mp) {
    half2v xsl[4], xsh[4];
#pragma unroll
    for (int b = 0; b < 4; ++b) {
      half2v p = *(const half2v*)(x0l + b * X0B + 2 * mp);  // m, m+1
      xsl[b] = (half2v){p.x, p.x};
      xsh[b] = (half2v){p.y, p.y};
    }
    do_group<NHI>(Wl, av, xsl, acc, 2 * mp);
    do_group<NHI>(Wl, av, xsh, acc, 2 * mp + 1);
  }

  // Epilogue (round-5 verified). C/D layout: col n = r, row d = q*4 + reg.
#pragma unroll
  for (int b = 0; b < 4; ++b) {
#pragma unroll
    for (int t = 0; t < 4; ++t) {
      float s = 0.f;
#pragma unroll
      for (int rr = 0; rr < 4; ++rr) {
        float v = acc[b][t][rr];
        v = v > 0.f ? v : 0.f;
        s += v;
        if (!LAST)
          xkw[b * XKB + (q * 4 + rr) * XKR + t * 16 + r] = (_Float16)v;
      }
      s += __shfl_xor(s, 16);
      s += __shfl_xor(s, 32);
      if (q == 0)
        out[(gb0 + b) * OUT_STRIDE + loff + t * 16 + r] = s;
    }
  }
}

__global__ __launch_bounds__(256, 3) void cin_main(
    const float* __restrict__ emb, const _Float16* __restrict__ Wall,
    float* __restrict__ out)
{
  // x0: 16 batches * 544 f16 (d-major pad-34) = 17408 B
  // xk: 16 batches * 1152 f16 (d rows, stride 72) = 36864 B
  // total 54272 B -> 3 blocks/CU (162816 <= 163840).
  __shared__ __align__(16) _Float16 lds[16 * X0B + 16 * XKB];
  const int lane = threadIdx.x & 63;
  const int wv = threadIdx.x >> 6;
  const int r = lane & 15, q = lane >> 4;
  const long gb0 = (long)blockIdx.x * 16 + wv * 4;

  _Float16* x0w = &lds[wv * 4 * X0B];
  _Float16* xkw = &lds[16 * X0B + wv * 4 * XKB];

  // Stage this wave's 4 batches: read (m,d) fp32, write transposed (d,m)
  // f16 at stride 34 (round-3-style scatter; measured fine there).
#pragma unroll
  for (int bb = 0; bb < 4; ++bb) {
    const float* src = emb + (gb0 + bb) * 512;
    _Float16* dstb = x0w + bb * X0B;
#pragma unroll
    for (int i = 0; i < 2; ++i) {
      int f = i * 256 + lane * 4;         // flat = m*16 + d, d aligned to 4
      float4 v = *(const float4*)(src + f);
      int m = f >> 4, d = f & 15;
      dstb[(d + 0) * X0R + m] = (_Float16)v.x;
      dstb[(d + 1) * X0R + m] = (_Float16)v.y;
      dstb[(d + 2) * X0R + m] = (_Float16)v.z;
      dstb[(d + 3) * X0R + m] = (_Float16)v.w;
    }
  }
  // All LDS regions are wave-private: program order + waitcnt suffice.

  // Layer 1: av from x0 (xk==x0, h along the m axis): d-major row r,
  // 8 consecutive halfs at m = q*8+j (one-time u16 reads, 4B-misaligned
  // rows so keep scalar).
  half8 av1[4][1];
#pragma unroll
  for (int b = 0; b < 4; ++b) {
#pragma unroll
    for (int j = 0; j < 8; ++j)
      av1[b][0][j] = x0w[b * X0B + r * X0R + q * 8 + j];
  }
  run_layer<1, false>(Wall, av1, x0w, xkw, out, gb0, 0, lane, r, q);

  // Layer 2: av from xk (h = hi*32 + q*8 + j), d-major xk layout.
  half8 av2[4][2];
#pragma unroll
  for (int b = 0; b < 4; ++b)
#pragma unroll
    for (int hi = 0; hi < 2; ++hi)
      av2[b][hi] = *(const half8*)(xkw + b * XKB + r * XKR + hi * 32 + q * 8);
  run_layer<2, false>(Wall + 65536, av2, x0w, xkw, out, gb0, 64, lane, r, q);

  // Layer 3: reload av (layer 2 rewrote xk).
#pragma unroll
  for (int b = 0; b < 4; ++b)
#pragma unroll
    for (int hi = 0; hi < 2; ++hi)
      av2[b][hi] = *(const half8*)(xkw + b * XKB + r * XKR + hi * 32 + q * 8);
  run_layer<2, true>(Wall + 196608, av2, x0w, xkw, out, gb0, 128, lane, r, q);
}

extern "C" void kernel_launch(void* const* d_in, const int* in_sizes, int n_in,
                              void* d_out, int out_size, void* d_ws, size_t ws_size,
                              hipStream_t stream) {
  const float* emb = (const float*)d_in[0];
  const float* W0  = (const float*)d_in[1];
  const float* W1  = (const float*)d_in[2];
  const float* W2  = (const float*)d_in[3];
  float* out = (float*)d_out;
  _Float16* ws = (_Float16*)d_ws;   // needs 327680 f16 = 640 KB

  // Fused weight repack, source-coalesced: 81920 float4 groups.
  prep_w_all<<<320, 256, 0, stream>>>(W0, W1, W2, ws);

  // 16384 batches / 16 per block = 1024 blocks of 256 threads (4 waves x 4 b).
  cin_main<<<1024, 256, 0, stream>>>(emb, ws, out);
}